// Round 1
// baseline (116.249 us; speedup 1.0000x reference)
//
#include <hip/hip_runtime.h>

// HamiltonianEvolution: the spectral gate is constant across the FFT axis,
// so FFT -> gate -> IFFT == elementwise multiply by gate[d]. The whole op
// collapses to a per-channel quaternion rotation:
//   out[b,t,:,d] = q_left_n[:,d] (*) (gate[d] * x[b,t,:,d]) (*) conj(q_right_n[:,d])
// Memory-bound: 64 MiB in + 64 MiB out.

constexpr int QD = 256;   // quat_dim
constexpr int DM = 1024;  // d_model = 4 * QD
constexpr float EPS = 1e-8f;

__global__ __launch_bounds__(256) void ham_evo_kernel(
    const float* __restrict__ x,
    const float* __restrict__ ql,
    const float* __restrict__ qr,
    const float* __restrict__ gate,
    float* __restrict__ out,
    int total)  // total = n_bt * (QD/4)
{
    const int tid0   = blockIdx.x * blockDim.x + threadIdx.x;
    const int stride = gridDim.x * blockDim.x;   // multiple of 64 -> d4 invariant
    const int d4     = (tid0 & 63) * 4;          // this thread's 4 channels

    // ---- Load quaternion params for channels d4..d4+3 (cached, tiny) ----
    float L[4][4], R[4][4], G[4];
    {
        float4 t;
        #pragma unroll
        for (int c = 0; c < 4; ++c) {
            t = *reinterpret_cast<const float4*>(ql + c * QD + d4);
            L[c][0] = t.x; L[c][1] = t.y; L[c][2] = t.z; L[c][3] = t.w;
            t = *reinterpret_cast<const float4*>(qr + c * QD + d4);
            R[c][0] = t.x; R[c][1] = t.y; R[c][2] = t.z; R[c][3] = t.w;
        }
        t = *reinterpret_cast<const float4*>(gate + d4);
        G[0] = t.x; G[1] = t.y; G[2] = t.z; G[3] = t.w;
    }

    // ---- Normalize left; normalize+conjugate right ----
    float pw[4], px[4], py[4], pz[4];
    float rw[4], rx[4], ry[4], rz[4];
    #pragma unroll
    for (int j = 0; j < 4; ++j) {
        float sl = L[0][j]*L[0][j] + L[1][j]*L[1][j] + L[2][j]*L[2][j] + L[3][j]*L[3][j] + EPS;
        float il = rsqrtf(sl);
        pw[j] = L[0][j]*il; px[j] = L[1][j]*il; py[j] = L[2][j]*il; pz[j] = L[3][j]*il;
        float sr = R[0][j]*R[0][j] + R[1][j]*R[1][j] + R[2][j]*R[2][j] + R[3][j]*R[3][j] + EPS;
        float ir = rsqrtf(sr);
        rw[j] =  R[0][j]*ir;
        rx[j] = -R[1][j]*ir;   // conjugate
        ry[j] = -R[2][j]*ir;
        rz[j] = -R[3][j]*ir;
    }

    // ---- Grid-stride over (b,t) rows; 4 channels x 4 components per thread ----
    for (int i = tid0; i < total; i += stride) {
        const int bt = i >> 6;
        const float* xb = x   + (size_t)bt * DM + d4;
        float*       ob = out + (size_t)bt * DM + d4;

        float4 vw = *reinterpret_cast<const float4*>(xb + 0 * QD);
        float4 vx = *reinterpret_cast<const float4*>(xb + 1 * QD);
        float4 vy = *reinterpret_cast<const float4*>(xb + 2 * QD);
        float4 vz = *reinterpret_cast<const float4*>(xb + 3 * QD);

        const float fw[4] = {vw.x, vw.y, vw.z, vw.w};
        const float fx[4] = {vx.x, vx.y, vx.z, vx.w};
        const float fy[4] = {vy.x, vy.y, vy.z, vy.w};
        const float fz[4] = {vz.x, vz.y, vz.z, vz.w};
        float ow[4], ox[4], oy[4], oz[4];

        #pragma unroll
        for (int j = 0; j < 4; ++j) {
            // apply gate (== the FFT round trip)
            const float aw = fw[j] * G[j];
            const float ax = fx[j] * G[j];
            const float ay = fy[j] * G[j];
            const float az = fz[j] * G[j];
            // t = a (*) conj(q_right_n)       [a is q1, rconj is q2]
            const float tw = aw*rw[j] - ax*rx[j] - ay*ry[j] - az*rz[j];
            const float tx = aw*rx[j] + ax*rw[j] + ay*rz[j] - az*ry[j];
            const float ty = aw*ry[j] - ax*rz[j] + ay*rw[j] + az*rx[j];
            const float tz = aw*rz[j] + ax*ry[j] - ay*rx[j] + az*rw[j];
            // o = q_left_n (*) t              [p is q1, t is q2]
            ow[j] = pw[j]*tw - px[j]*tx - py[j]*ty - pz[j]*tz;
            ox[j] = pw[j]*tx + px[j]*tw + py[j]*tz - pz[j]*ty;
            oy[j] = pw[j]*ty - px[j]*tz + py[j]*tw + pz[j]*tx;
            oz[j] = pw[j]*tz + px[j]*ty - py[j]*tx + pz[j]*tw;
        }

        *reinterpret_cast<float4*>(ob + 0 * QD) = make_float4(ow[0], ow[1], ow[2], ow[3]);
        *reinterpret_cast<float4*>(ob + 1 * QD) = make_float4(ox[0], ox[1], ox[2], ox[3]);
        *reinterpret_cast<float4*>(ob + 2 * QD) = make_float4(oy[0], oy[1], oy[2], oy[3]);
        *reinterpret_cast<float4*>(ob + 3 * QD) = make_float4(oz[0], oz[1], oz[2], oz[3]);
    }
}

extern "C" void kernel_launch(void* const* d_in, const int* in_sizes, int n_in,
                              void* d_out, int out_size, void* d_ws, size_t ws_size,
                              hipStream_t stream) {
    const float* x    = (const float*)d_in[0];
    const float* ql   = (const float*)d_in[1];
    const float* qr   = (const float*)d_in[2];
    const float* gate = (const float*)d_in[3];
    float* out = (float*)d_out;

    const int n_bt  = out_size / DM;          // B*T rows
    const int total = n_bt * (QD / 4);        // one thread per (row, 4-channel group)

    const int block = 256;
    int grid = (total + block - 1) / block;
    if (grid > 2048) grid = 2048;             // grid-stride the rest

    ham_evo_kernel<<<grid, block, 0, stream>>>(x, ql, qr, gate, out, total);
}